// Round 15
// baseline (567.458 us; speedup 1.0000x reference)
//
#include <hip/hip_runtime.h>
#include <hip/hip_bf16.h>

typedef __attribute__((ext_vector_type(4))) float f4v;
typedef __attribute__((ext_vector_type(4))) short s4v;
typedef __attribute__((ext_vector_type(8))) short s8v;

#define DEVINL __device__ __forceinline__
#define NBLK 128
#define PADK 536          // 512 + 24 shorts padding
#define WROWS (16 * PADK) // shorts per weight slice
#define HSLOT 16384       // shorts per h slot (32 batches x 512 dims)

DEVINL short f2bf(float f) {
  unsigned u = __float_as_uint(f);
  u += 0x7FFFu + ((u >> 16) & 1u);
  return (short)(u >> 16);
}
DEVINL float bf2f(short s) {
  return __uint_as_float(((unsigned)(unsigned short)s) << 16);
}
DEVINL float sigm(float x) { return 1.f / (1.f + expf(-x)); }

// coherent (write-through past L2) 8-byte store
DEVINL void cstore64(short* p, unsigned long long d) {
  asm volatile("global_store_dwordx2 %0, %1, off sc0 sc1"
               :: "v"(p), "v"(d) : "memory");
}

// ---- init: h0,h1 (bf16) into slot-0 buffers; zero flag words ---------------
__global__ __launch_bounds__(256) void k_init2(const float* __restrict__ enc_h,
                                               short* __restrict__ hbuf,
                                               unsigned* __restrict__ arr) {
  int i = blockIdx.x * 256 + threadIdx.x;  // 0..16383
  hbuf[i] = f2bf(enc_h[i]);                            // H0 slot0
  hbuf[(long)65 * HSLOT + i] = f2bf(enc_h[16384 + i]); // H1 slot0
  if (i < NBLK * 32 + 32) arr[i] = 0u;
}

// ---- w_enc[j] = sum_k attn2_w[k] * attn1_w[k*2048 + j], j<1024 -------------
__global__ __launch_bounds__(256) void k_weff(const float* __restrict__ attn1_w,
                                              const float* __restrict__ attn2_w,
                                              float* __restrict__ w_enc) {
  __shared__ float part[8][32];
  int t = threadIdx.x;
  int jl = t & 31, kp = t >> 5;
  int j = blockIdx.x * 32 + jl;
  float acc = 0.f;
  for (int k = kp * 256; k < kp * 256 + 256; ++k)
    acc += attn2_w[k] * attn1_w[(long)k * 2048 + j];
  part[kp][jl] = acc;
  __syncthreads();
  if (t < 32) {
    float s = 0.f;
    for (int p = 0; p < 8; ++p) s += part[p][t];
    w_enc[blockIdx.x * 32 + t] = s;
  }
}

// ---- logits[b][s] = enc[b,s,:] . w_enc  (256 blocks: 32 b x 8 s-chunks) ----
__global__ __launch_bounds__(256) void k_attn_lg(const float* __restrict__ enc,
                                                 const float* __restrict__ w_enc,
                                                 float* __restrict__ logits) {
  __shared__ float red[16][17];
  int b = blockIdx.x >> 3, sp = blockIdx.x & 7;
  int t = threadIdx.x, row = t >> 4, kc = t & 15;
  int s = sp * 16 + row;
  const float* e = enc + ((long)b * 128 + s) * 1024 + kc * 64;
  const float* wv = w_enc + kc * 64;
  float acc = 0.f;
  for (int k = 0; k < 64; k += 4) {
    f4v ev = *(const f4v*)(e + k);
    f4v w4 = *(const f4v*)(wv + k);
    acc += ev[0] * w4[0] + ev[1] * w4[1] + ev[2] * w4[2] + ev[3] * w4[3];
  }
  red[row][kc] = acc;
  __syncthreads();
  if (kc == 0) {
    float sm = 0.f;
#pragma unroll
    for (int i = 0; i < 16; ++i) sm += red[row][i];
    logits[b * 128 + s] = sm;
  }
}

// ---- ctx[b][dim] via softmax(logits[b]) . enc  (128 blocks: 32 b x 4 chunks)
__global__ __launch_bounds__(256) void k_attn_cx(const float* __restrict__ enc,
                                                 const float* __restrict__ logits,
                                                 float* __restrict__ ctx) {
  __shared__ float wls[128];
  __shared__ float red[256];
  int b = blockIdx.x >> 2, ch = blockIdx.x & 3;
  int t = threadIdx.x;
  float lv = (t < 128) ? logits[b * 128 + t] : -3.4e38f;
  red[t] = lv;
  __syncthreads();
  for (int off = 128; off >= 1; off >>= 1) {
    if (t < off) red[t] = fmaxf(red[t], red[t + off]);
    __syncthreads();
  }
  float mx = red[0];
  __syncthreads();
  float ex = 0.f;
  if (t < 128) { ex = expf(lv - mx); wls[t] = ex; }
  red[t] = ex;
  __syncthreads();
  for (int off = 128; off >= 1; off >>= 1) {
    if (t < off) red[t] += red[t + off];
    __syncthreads();
  }
  float inv = 1.f / red[0];
  int dim = ch * 256 + t;
  const float* eb = enc + (long)b * 131072 + dim;
  float a = 0.f;
#pragma unroll 4
  for (int ss = 0; ss < 128; ++ss) a += wls[ss] * eb[ss * 1024];
  ctx[b * 1024 + dim] = a * inv;
}

// ---- ctxpre[b][j] = ctx[b] . w_ih0[j, 512:1536] + b_ih0[j] + b_hh0[j] ------
__global__ __launch_bounds__(256) void k_ctxpre(const float* __restrict__ w_ih0,
                                                const float* __restrict__ b_ih0,
                                                const float* __restrict__ b_hh0,
                                                const float* __restrict__ ctx,
                                                float* __restrict__ ctxpre) {
  int t = threadIdx.x;
  int j = blockIdx.x * 8 + (t >> 5);
  int b = t & 31;
  float acc = b_ih0[j] + b_hh0[j];
  const float* w = w_ih0 + (long)j * 1536 + 512;
  const float* c = ctx + b * 1024;
  for (int k = 0; k < 1024; k += 4) {
    f4v wv = *(const f4v*)(w + k);
    f4v cv = *(const f4v*)(c + k);
    acc += wv[0] * cv[0] + wv[1] * cv[1] + wv[2] * cv[2] + wv[3] * cv[3];
  }
  ctxpre[b * 2048 + j] = acc;
}

// ---- fp32 out_w -> bf16 -----------------------------------------------------
__global__ __launch_bounds__(256) void k_cvt(const float* __restrict__ src,
                                             short* __restrict__ dst) {
  long i = ((long)blockIdx.x * 256 + threadIdx.x) * 8;
  f4v a = *(const f4v*)(src + i);
  f4v b = *(const f4v*)(src + i + 4);
  s8v o;
  o[0] = f2bf(a[0]); o[1] = f2bf(a[1]); o[2] = f2bf(a[2]); o[3] = f2bf(a[3]);
  o[4] = f2bf(b[0]); o[5] = f2bf(b[1]); o[6] = f2bf(b[2]); o[7] = f2bf(b[3]);
  *(s8v*)(dst + i) = o;
}

// ---- fp32-input bf16 MFMA GEMM (MODE 2: scatter to embp2 packed layout) ----
template <int MODE>
__global__ __launch_bounds__(256) void gemm_bf16(
    const float* __restrict__ A, const float* __restrict__ B,
    const int* __restrict__ a_rows, const float* __restrict__ bias,
    float* __restrict__ C, int K, int lda, int ldb, int ldc) {
  __shared__ short As[128 * 72];
  __shared__ short Bs[128 * 72];
  int n0 = blockIdx.x * 128, m0 = blockIdx.y * 128;
  int t = threadIdx.x;
  int lane = t & 63, w = t >> 6;
  int wm = w & 1, wn = w >> 1;
  f4v acc[4][4];
#pragma unroll
  for (int mi = 0; mi < 4; ++mi)
#pragma unroll
    for (int ni = 0; ni < 4; ++ni) acc[mi][ni] = (f4v){0.f, 0.f, 0.f, 0.f};

  int sr = t >> 1;
  int sh = (t & 1) * 32;
  long arow = a_rows ? (long)a_rows[m0 + sr] : (long)(m0 + sr);
  const float* ap = A + arow * lda + sh;
  const float* bp = B + (long)(n0 + sr) * ldb + sh;
  short* as = &As[sr * 72 + sh];
  short* bs = &Bs[sr * 72 + sh];

  for (int k0 = 0; k0 < K; k0 += 64) {
#pragma unroll
    for (int i = 0; i < 8; ++i) {
      f4v va = *(const f4v*)(ap + k0 + i * 4);
      f4v vb = *(const f4v*)(bp + k0 + i * 4);
      s4v sa, sb;
      sa[0] = f2bf(va[0]); sa[1] = f2bf(va[1]); sa[2] = f2bf(va[2]); sa[3] = f2bf(va[3]);
      sb[0] = f2bf(vb[0]); sb[1] = f2bf(vb[1]); sb[2] = f2bf(vb[2]); sb[3] = f2bf(vb[3]);
      *(s4v*)(as + i * 4) = sa;
      *(s4v*)(bs + i * 4) = sb;
    }
    __syncthreads();
#pragma unroll
    for (int ks = 0; ks < 2; ++ks) {
      s8v af[4], bf[4];
#pragma unroll
      for (int mi = 0; mi < 4; ++mi)
        af[mi] = *(const s8v*)&As[(wm * 64 + mi * 16 + (lane & 15)) * 72 + ks * 32 + (lane >> 4) * 8];
#pragma unroll
      for (int ni = 0; ni < 4; ++ni)
        bf[ni] = *(const s8v*)&Bs[(wn * 64 + ni * 16 + (lane & 15)) * 72 + ks * 32 + (lane >> 4) * 8];
#pragma unroll
      for (int mi = 0; mi < 4; ++mi)
#pragma unroll
        for (int ni = 0; ni < 4; ++ni)
          acc[mi][ni] = __builtin_amdgcn_mfma_f32_16x16x32_bf16(af[mi], bf[ni], acc[mi][ni], 0, 0, 0);
    }
    __syncthreads();
  }
  int fq = lane >> 4, fr = lane & 15;
#pragma unroll
  for (int mi = 0; mi < 4; ++mi)
#pragma unroll
    for (int ni = 0; ni < 4; ++ni) {
      int col = n0 + wn * 64 + ni * 16 + fr;
      long rowb = m0 + wm * 64 + mi * 16 + fq * 4;
      if (MODE == 2) {
        int bz = (col & 511) >> 2;
        int c = ((col >> 9) << 2) + (col & 3);
#pragma unroll
        for (int r = 0; r < 4; ++r) {
          long m = rowb + r;  // = b*64 + t
          C[(long)bz * 32768 + (m & 63) * 512 + (m >> 6) * 16 + c] = acc[mi][ni][r];
        }
      } else {
        float bv = bias ? bias[col] : 0.f;
#pragma unroll
        for (int r = 0; r < 4; ++r) C[(rowb + r) * (long)ldc + col] = acc[mi][ni][r] + bv;
      }
    }
}

// ---- output GEMM: A bf16 [2048][512], B bf16 (or fp32 if BCVT) [32000][512] -
// XCD-colocated 1-D grid: xcd = id&7, q = id>>3, m_t = q&15, n_t = (q>>4)*8+xcd
// -> all 16 m-tiles of one n-slice run consecutively on ONE XCD: the 128 KB
// B-slice and the whole 2 MB A stay L2-resident (fetch ~50 MB vs ~270 MB).
// OPERAND-SWAPPED MFMA: lane holds 4 consecutive n for one m -> dwordx4 store.
template <bool BCVT>
__global__ __launch_bounds__(256) void gemm_out(
    const short* __restrict__ A, const short* __restrict__ Bbf,
    const float* __restrict__ Bf, const float* __restrict__ bias,
    float* __restrict__ C) {
  __shared__ short As[128 * 72];
  __shared__ short Bs[128 * 72];
  int id = blockIdx.x;
  int xcd = id & 7, q = id >> 3;
  int n_t = (q >> 4) * 8 + xcd;
  if (n_t >= 250) return;
  int m0 = (q & 15) * 128, n0 = n_t * 128;
  int t = threadIdx.x;
  int lane = t & 63, w = t >> 6;
  int wm = w & 1, wn = w >> 1;
  f4v acc[4][4];
#pragma unroll
  for (int mi = 0; mi < 4; ++mi)
#pragma unroll
    for (int ni = 0; ni < 4; ++ni) acc[mi][ni] = (f4v){0.f, 0.f, 0.f, 0.f};

  int sr = t >> 1;
  int sh = (t & 1) * 32;
  const short* ap = A + (long)(m0 + sr) * 512 + sh;
  const short* bpb = Bbf + (long)(n0 + sr) * 512 + sh;
  const float* bpf = Bf + (long)(n0 + sr) * 512 + sh;
  short* as = &As[sr * 72 + sh];
  short* bs = &Bs[sr * 72 + sh];

  for (int k0 = 0; k0 < 512; k0 += 64) {
#pragma unroll
    for (int i = 0; i < 4; ++i)
      *(s8v*)(as + i * 8) = *(const s8v*)(ap + k0 + i * 8);
    if (BCVT) {
#pragma unroll
      for (int i = 0; i < 8; ++i) {
        f4v vb = *(const f4v*)(bpf + k0 + i * 4);
        s4v sb;
        sb[0] = f2bf(vb[0]); sb[1] = f2bf(vb[1]); sb[2] = f2bf(vb[2]); sb[3] = f2bf(vb[3]);
        *(s4v*)(bs + i * 4) = sb;
      }
    } else {
#pragma unroll
      for (int i = 0; i < 4; ++i)
        *(s8v*)(bs + i * 8) = *(const s8v*)(bpb + k0 + i * 8);
    }
    __syncthreads();
#pragma unroll
    for (int ks = 0; ks < 2; ++ks) {
      s8v af[4], bf[4];
#pragma unroll
      for (int mi = 0; mi < 4; ++mi)
        af[mi] = *(const s8v*)&As[(wm * 64 + mi * 16 + (lane & 15)) * 72 + ks * 32 + (lane >> 4) * 8];
#pragma unroll
      for (int ni = 0; ni < 4; ++ni)
        bf[ni] = *(const s8v*)&Bs[(wn * 64 + ni * 16 + (lane & 15)) * 72 + ks * 32 + (lane >> 4) * 8];
#pragma unroll
      for (int mi = 0; mi < 4; ++mi)
#pragma unroll
        for (int ni = 0; ni < 4; ++ni)
          acc[mi][ni] = __builtin_amdgcn_mfma_f32_16x16x32_bf16(bf[ni], af[mi], acc[mi][ni], 0, 0, 0);
    }
    __syncthreads();
  }
  int fq = lane >> 4, fr = lane & 15;
#pragma unroll
  for (int mi = 0; mi < 4; ++mi) {
    long m = m0 + wm * 64 + mi * 16 + fr;
#pragma unroll
    for (int ni = 0; ni < 4; ++ni) {
      int nb = n0 + wn * 64 + ni * 16 + fq * 4;
      f4v bv = *(const f4v*)&bias[nb];
      f4v val = acc[mi][ni] + bv;
      __builtin_nontemporal_store(val, (f4v*)&C[m * 32000L + nb]);
    }
  }
}

// ---- persistent fused 2-layer LSTM: BLOCK-SPECIALIZED twin pipelines --------
// (r9 structure — proven 317 us.) 256 blocks x 256 threads: [0,128) = layer-0
// pipeline (owns 4 h0-dims), [128,256) = layer-1 pipeline (owns 4 h1-dims).
__global__ __launch_bounds__(256, 1) void lstm_persist(
    const float* __restrict__ w_hh0, const float* __restrict__ w_ih1,
    const float* __restrict__ w_hh1,
    const float* __restrict__ b_ih1, const float* __restrict__ b_hh1,
    const float* __restrict__ enc_c,
    const float* __restrict__ embp2, const float* __restrict__ ctxpre,
    short* __restrict__ hbuf, short* __restrict__ h1seqbf,
    unsigned* __restrict__ arr) {
  __shared__ alignas(16) short wlds[6 * WROWS];  // l0: 2 slices; l1: 4 slices
  __shared__ float ctxp_l[32][16];               // l0 only
  __shared__ float bias1_l[16];                  // l1 only
  __shared__ float gbuf[2][32][17];              // [kh][batch][gatecol]

  const int tid = threadIdx.x;
  const bool is_l0 = (blockIdx.x < NBLK);
  const int bz = is_l0 ? blockIdx.x : blockIdx.x - NBLK;
  const int hb4 = bz * 4;
  const int lane = tid & 63, wid = tid >> 6;
  const int mt = wid & 1, kh = wid >> 1;
  const int fr = lane & 15, fq = lane >> 4;

  const int nmat = is_l0 ? 1 : 2;
  for (int base = tid * 4; base < nmat * 16 * 512; base += 1024) {
    int row = base >> 9, k = base & 511;
    int m = row >> 4, c = row & 15;
    int j = ((c >> 2) << 9) + hb4 + (c & 3);
    const float* wsrc = is_l0 ? w_hh0 : (m == 0 ? w_ih1 : w_hh1);
    f4v v = *(const f4v*)(wsrc + (long)j * 512 + k);
    short* hi = &wlds[(m * 2) * WROWS + c * PADK + k];
    short* lo = &wlds[(m * 2 + 1) * WROWS + c * PADK + k];
#pragma unroll
    for (int e = 0; e < 4; ++e) {
      short hh = f2bf(v[e]);
      hi[e] = hh;
      lo[e] = f2bf(v[e] - bf2f(hh));
    }
  }
  if (is_l0) {
    for (int i = tid; i < 512; i += 256) {
      int b = i >> 4, c = i & 15;
      ctxp_l[b][c] = ctxpre[b * 2048 + ((c >> 2) << 9) + hb4 + (c & 3)];
    }
  } else if (tid < 16) {
    int j = ((tid >> 2) << 9) + hb4 + (tid & 3);
    bias1_l[tid] = b_ih1[j] + b_hh1[j];
  }
  const int cq = (tid & 127) >> 2, cr = tid & 3;
  float cst = 0.f;
  if (tid < 128)
    cst = enc_c[(is_l0 ? 0 : 16384) + cq * 512 + hb4 + cr];
  __syncthreads();
  asm volatile("s_waitcnt vmcnt(0)" ::: "memory");
  asm volatile("buffer_inv sc1" ::: "memory");
  __syncthreads();

  short* H0 = hbuf;                        // + slot*HSLOT
  short* H1 = hbuf + (long)65 * HSLOT;
  const int foff = (mt * 16 + fr) * 512 + kh * 256 + fq * 8;
  const int woff = fr * PADK + kh * 256 + fq * 8;

  if (is_l0) {
    // =================== layer-0 pipeline: p = 0..63 =====================
    for (int p = 0; p < 64; ++p) {
      float e4[4];
      if (tid < 128) {
        const float* ep = embp2 + (long)bz * 32768 + p * 512 + cq * 16 + cr;
#pragma unroll
        for (int g = 0; g < 4; ++g) e4[g] = ep[g * 4];
      }
      if (p) {
        if (tid < NBLK)
          while (__hip_atomic_load(&arr[tid << 5], __ATOMIC_RELAXED,
                                   __HIP_MEMORY_SCOPE_AGENT) < (unsigned)p)
            __builtin_amdgcn_s_sleep(1);
        __syncthreads();
      }
      const short* a0 = H0 + (long)p * HSLOT + foff;
      f4v l0h = {0.f, 0.f, 0.f, 0.f}, l0l = l0h;
      const short* b0h = &wlds[0 * WROWS + woff];
      const short* b0l = &wlds[1 * WROWS + woff];
#pragma unroll
      for (int ks = 0; ks < 8; ++ks) {
        s8v A0 = *(const s8v*)(a0 + ks * 32);
        s8v B0h = *(const s8v*)(b0h + ks * 32);
        s8v B0l = *(const s8v*)(b0l + ks * 32);
        l0h = __builtin_amdgcn_mfma_f32_16x16x32_bf16(A0, B0h, l0h, 0, 0, 0);
        l0l = __builtin_amdgcn_mfma_f32_16x16x32_bf16(A0, B0l, l0l, 0, 0, 0);
      }
      f4v s = l0h + l0l;
#pragma unroll
      for (int r = 0; r < 4; ++r) gbuf[kh][mt * 16 + fq * 4 + r][fr] = s[r];
      __syncthreads();
      if (tid < 128) {
        float g4[4];
#pragma unroll
        for (int g = 0; g < 4; ++g) {
          int c = g * 4 + cr;
          g4[g] = gbuf[0][cq][c] + gbuf[1][cq][c] + ctxp_l[cq][c] + e4[g];
        }
        float cn = sigm(g4[1]) * cst + sigm(g4[0]) * tanhf(g4[2]);
        float hn = sigm(g4[3]) * tanhf(cn);
        cst = cn;
        unsigned v16 = (unsigned)(unsigned short)f2bf(hn);
        unsigned p01 = v16 | ((unsigned)__shfl_down((int)v16, 1) << 16);
        unsigned long long wd = (unsigned long long)p01 |
            ((unsigned long long)(unsigned)__shfl_down((int)p01, 2) << 32);
        if ((tid & 3) == 0)
          cstore64(H0 + (long)(p + 1) * HSLOT + cq * 512 + hb4, wd);
      }
      asm volatile("s_waitcnt vmcnt(0)" ::: "memory");
      __syncthreads();
      if (tid == 0)
        __hip_atomic_store(&arr[(unsigned)bz << 5], (unsigned)(p + 1),
                           __ATOMIC_RELAXED, __HIP_MEMORY_SCOPE_AGENT);
    }
  } else {
    // =================== layer-1 pipeline: p = 1..64 =====================
    for (int p = 1; p <= 64; ++p) {
      if (tid < NBLK)
        while (__hip_atomic_load(&arr[tid << 5], __ATOMIC_RELAXED,
                                 __HIP_MEMORY_SCOPE_AGENT) < (unsigned)p)
          __builtin_amdgcn_s_sleep(2);
      __syncthreads();
      const short* a0 = H0 + (long)p * HSLOT + foff;
      f4v x1h = {0.f, 0.f, 0.f, 0.f}, x1l = x1h, h1h = x1h, h1l = x1h;
      const short* b2h = &wlds[0 * WROWS + woff];
      const short* b2l = &wlds[1 * WROWS + woff];
#pragma unroll
      for (int ks = 0; ks < 8; ++ks) {
        s8v A0 = *(const s8v*)(a0 + ks * 32);
        s8v B2h = *(const s8v*)(b2h + ks * 32);
        s8v B2l = *(const s8v*)(b2l + ks * 32);
        x1h = __builtin_amdgcn_mfma_f32_16x16x32_bf16(A0, B2h, x1h, 0, 0, 0);
        x1l = __builtin_amdgcn_mfma_f32_16x16x32_bf16(A0, B2l, x1l, 0, 0, 0);
      }
      if (p > 1) {
        if (tid < NBLK)
          while (__hip_atomic_load(&arr[(tid << 5) + 16], __ATOMIC_RELAXED,
                                   __HIP_MEMORY_SCOPE_AGENT) < (unsigned)(p - 1))
            __builtin_amdgcn_s_sleep(2);
        __syncthreads();
      }
      const short* a1 = H1 + (long)(p - 1) * HSLOT + foff;
      const short* b4h = &wlds[2 * WROWS + woff];
      const short* b4l = &wlds[3 * WROWS + woff];
#pragma unroll
      for (int ks = 0; ks < 8; ++ks) {
        s8v A1 = *(const s8v*)(a1 + ks * 32);
        s8v B4h = *(const s8v*)(b4h + ks * 32);
        s8v B4l = *(const s8v*)(b4l + ks * 32);
        h1h = __builtin_amdgcn_mfma_f32_16x16x32_bf16(A1, B4h, h1h, 0, 0, 0);
        h1l = __builtin_amdgcn_mfma_f32_16x16x32_bf16(A1, B4l, h1l, 0, 0, 0);
      }
      f4v s = x1h + x1l + h1h + h1l;
#pragma unroll
      for (int r = 0; r < 4; ++r) gbuf[kh][mt * 16 + fq * 4 + r][fr] = s[r];
      __syncthreads();
      if (tid < 128) {
        float g4[4];
#pragma unroll
        for (int g = 0; g < 4; ++g) {
          int c = g * 4 + cr;
          g4[g] = gbuf[0][cq][c] + gbuf[1][cq][c] + bias1_l[c];
        }
        float cn = sigm(g4[1]) * cst + sigm(g4[0]) * tanhf(g4[2]);
        float hn = sigm(g4[3]) * tanhf(cn);
        cst = cn;
        unsigned v16 = (unsigned)(unsigned short)f2bf(hn);
        unsigned p01 = v16 | ((unsigned)__shfl_down((int)v16, 1) << 16);
        unsigned long long wd = (unsigned long long)p01 |
            ((unsigned long long)(unsigned)__shfl_down((int)p01, 2) << 32);
        if ((tid & 3) == 0) {
          if (p < 64)  // slot 64 never read (h1seq carries step 63)
            cstore64(H1 + (long)p * HSLOT + cq * 512 + hb4, wd);
          *(unsigned long long*)&h1seqbf[((long)cq * 64 + (p - 1)) * 512 + hb4] = wd;
        }
      }
      if (p < 64) {
        asm volatile("s_waitcnt vmcnt(0)" ::: "memory");
        __syncthreads();
        if (tid == 0)
          __hip_atomic_store(&arr[((unsigned)bz << 5) + 16], (unsigned)p,
                             __ATOMIC_RELAXED, __HIP_MEMORY_SCOPE_AGENT);
      }
    }
  }
}

extern "C" void kernel_launch(void* const* d_in, const int* in_sizes, int n_in,
                              void* d_out, int out_size, void* d_ws, size_t ws_size,
                              hipStream_t stream) {
  const int*   tokens  = (const int*)  d_in[0];
  const float* enc_out = (const float*)d_in[1];
  const float* enc_h   = (const float*)d_in[2];
  const float* enc_c   = (const float*)d_in[3];
  const float* emb     = (const float*)d_in[4];
  const float* attn1_w = (const float*)d_in[5];
  const float* attn2_w = (const float*)d_in[7];
  const float* w_ih0   = (const float*)d_in[9];
  const float* w_hh0   = (const float*)d_in[10];
  const float* b_ih0   = (const float*)d_in[11];
  const float* b_hh0   = (const float*)d_in[12];
  const float* w_ih1   = (const float*)d_in[13];
  const float* w_hh1   = (const float*)d_in[14];
  const float* b_ih1   = (const float*)d_in[15];
  const float* b_hh1   = (const float*)d_in[16];
  const float* out_w   = (const float*)d_in[17];
  const float* out_b   = (const float*)d_in[18];
  float* out = (float*)d_out;

  float* f = (float*)d_ws;
  float*    w_enc    = f;                        // [0, 1024)
  float*    ctx      = f + 1024;                 // [1024, 33792)
  float*    ctxpre   = f + 33792;                // [33792, 99328)
  float*    embp2    = f + 99328;                // [99328, 4293632)
  short*    h1seqbf  = (short*)(f + 4293632);    // 1,048,576 shorts -> 4817920
  short*    hbuf     = (short*)(f + 4817920);    // 130 x 16384 shorts -> 5882880
  unsigned* arr      = (unsigned*)(f + 5882880); // 4128 uints -> 5887008
  float*    logits   = f + 5887040;              // 4096 floats -> 5891136
  short*    out_w_bf = (short*)(f + 5891200);    // 16,384,000 shorts (optional)
  const size_t NEED = (size_t)(5891200 + 8192000) * 4;
  const bool big = ws_size >= NEED;

  k_init2<<<64, 256, 0, stream>>>(enc_h, hbuf, arr);
  k_weff<<<32, 256, 0, stream>>>(attn1_w, attn2_w, w_enc);
  k_attn_lg<<<256, 256, 0, stream>>>(enc_out, w_enc, logits);
  k_attn_cx<<<128, 256, 0, stream>>>(enc_out, logits, ctx);
  k_ctxpre<<<256, 256, 0, stream>>>(w_ih0, b_ih0, b_hh0, ctx, ctxpre);
  gemm_bf16<2><<<dim3(16, 16), 256, 0, stream>>>(emb, w_ih0, tokens, nullptr,
                                                 embp2, 512, 512, 1536, 0);
  if (big) k_cvt<<<8000, 256, 0, stream>>>(out_w, out_w_bf);
  lstm_persist<<<2 * NBLK, 256, 0, stream>>>(w_hh0, w_ih1, w_hh1, b_ih1, b_hh1,
                                             enc_c, embp2, ctxpre, hbuf,
                                             h1seqbf, arr);
  if (big)
    gemm_out<false><<<4096, 256, 0, stream>>>(h1seqbf, out_w_bf, nullptr,
                                              out_b, out);
  else
    gemm_out<true><<<4096, 256, 0, stream>>>(h1seqbf, nullptr, out_w,
                                             out_b, out);
}

// Round 16
// 545.289 us; speedup vs baseline: 1.0407x; 1.0407x over previous
//
#include <hip/hip_runtime.h>
#include <hip/hip_bf16.h>

typedef __attribute__((ext_vector_type(4))) float f4v;
typedef __attribute__((ext_vector_type(4))) short s4v;
typedef __attribute__((ext_vector_type(8))) short s8v;

#define DEVINL __device__ __forceinline__
#define NBLK 128
#define PADK 536          // 512 + 24 shorts padding
#define WROWS (16 * PADK) // shorts per weight slice
#define HSLOT 16384       // shorts per h slot (32 batches x 512 dims)

DEVINL short f2bf(float f) {
  unsigned u = __float_as_uint(f);
  u += 0x7FFFu + ((u >> 16) & 1u);
  return (short)(u >> 16);
}
DEVINL float bf2f(short s) {
  return __uint_as_float(((unsigned)(unsigned short)s) << 16);
}
DEVINL float sigm(float x) { return 1.f / (1.f + expf(-x)); }

// coherent (write-through past L2) 8-byte store
DEVINL void cstore64(short* p, unsigned long long d) {
  asm volatile("global_store_dwordx2 %0, %1, off sc0 sc1"
               :: "v"(p), "v"(d) : "memory");
}

// ---- init: h0,h1 (bf16) into slot-0 buffers; zero flag words ---------------
__global__ __launch_bounds__(256) void k_init2(const float* __restrict__ enc_h,
                                               short* __restrict__ hbuf,
                                               unsigned* __restrict__ arr) {
  int i = blockIdx.x * 256 + threadIdx.x;  // 0..16383
  hbuf[i] = f2bf(enc_h[i]);                            // H0 slot0
  hbuf[(long)65 * HSLOT + i] = f2bf(enc_h[16384 + i]); // H1 slot0
  if (i < NBLK * 32 + 32) arr[i] = 0u;
}

// ---- w_enc[j] = sum_k attn2_w[k] * attn1_w[k*2048 + j], j<1024 -------------
__global__ __launch_bounds__(256) void k_weff(const float* __restrict__ attn1_w,
                                              const float* __restrict__ attn2_w,
                                              float* __restrict__ w_enc) {
  __shared__ float part[8][32];
  int t = threadIdx.x;
  int jl = t & 31, kp = t >> 5;
  int j = blockIdx.x * 32 + jl;
  float acc = 0.f;
  for (int k = kp * 256; k < kp * 256 + 256; ++k)
    acc += attn2_w[k] * attn1_w[(long)k * 2048 + j];
  part[kp][jl] = acc;
  __syncthreads();
  if (t < 32) {
    float s = 0.f;
    for (int p = 0; p < 8; ++p) s += part[p][t];
    w_enc[blockIdx.x * 32 + t] = s;
  }
}

// ---- logits[b][s] = enc[b,s,:] . w_enc  (256 blocks: 32 b x 8 s-chunks) ----
__global__ __launch_bounds__(256) void k_attn_lg(const float* __restrict__ enc,
                                                 const float* __restrict__ w_enc,
                                                 float* __restrict__ logits) {
  __shared__ float red[16][17];
  int b = blockIdx.x >> 3, sp = blockIdx.x & 7;
  int t = threadIdx.x, row = t >> 4, kc = t & 15;
  int s = sp * 16 + row;
  const float* e = enc + ((long)b * 128 + s) * 1024 + kc * 64;
  const float* wv = w_enc + kc * 64;
  float acc = 0.f;
  for (int k = 0; k < 64; k += 4) {
    f4v ev = *(const f4v*)(e + k);
    f4v w4 = *(const f4v*)(wv + k);
    acc += ev[0] * w4[0] + ev[1] * w4[1] + ev[2] * w4[2] + ev[3] * w4[3];
  }
  red[row][kc] = acc;
  __syncthreads();
  if (kc == 0) {
    float sm = 0.f;
#pragma unroll
    for (int i = 0; i < 16; ++i) sm += red[row][i];
    logits[b * 128 + s] = sm;
  }
}

// ---- ctx[b][dim] via softmax(logits[b]) . enc  (128 blocks: 32 b x 4 chunks)
__global__ __launch_bounds__(256) void k_attn_cx(const float* __restrict__ enc,
                                                 const float* __restrict__ logits,
                                                 float* __restrict__ ctx) {
  __shared__ float wls[128];
  __shared__ float red[256];
  int b = blockIdx.x >> 2, ch = blockIdx.x & 3;
  int t = threadIdx.x;
  float lv = (t < 128) ? logits[b * 128 + t] : -3.4e38f;
  red[t] = lv;
  __syncthreads();
  for (int off = 128; off >= 1; off >>= 1) {
    if (t < off) red[t] = fmaxf(red[t], red[t + off]);
    __syncthreads();
  }
  float mx = red[0];
  __syncthreads();
  float ex = 0.f;
  if (t < 128) { ex = expf(lv - mx); wls[t] = ex; }
  red[t] = ex;
  __syncthreads();
  for (int off = 128; off >= 1; off >>= 1) {
    if (t < off) red[t] += red[t + off];
    __syncthreads();
  }
  float inv = 1.f / red[0];
  int dim = ch * 256 + t;
  const float* eb = enc + (long)b * 131072 + dim;
  float a = 0.f;
#pragma unroll 4
  for (int ss = 0; ss < 128; ++ss) a += wls[ss] * eb[ss * 1024];
  ctx[b * 1024 + dim] = a * inv;
}

// ---- ctxpre[b][j] = ctx[b] . w_ih0[j, 512:1536] + b_ih0[j] + b_hh0[j] ------
__global__ __launch_bounds__(256) void k_ctxpre(const float* __restrict__ w_ih0,
                                                const float* __restrict__ b_ih0,
                                                const float* __restrict__ b_hh0,
                                                const float* __restrict__ ctx,
                                                float* __restrict__ ctxpre) {
  int t = threadIdx.x;
  int j = blockIdx.x * 8 + (t >> 5);
  int b = t & 31;
  float acc = b_ih0[j] + b_hh0[j];
  const float* w = w_ih0 + (long)j * 1536 + 512;
  const float* c = ctx + b * 1024;
  for (int k = 0; k < 1024; k += 4) {
    f4v wv = *(const f4v*)(w + k);
    f4v cv = *(const f4v*)(c + k);
    acc += wv[0] * cv[0] + wv[1] * cv[1] + wv[2] * cv[2] + wv[3] * cv[3];
  }
  ctxpre[b * 2048 + j] = acc;
}

// ---- fp32 out_w -> bf16 -----------------------------------------------------
__global__ __launch_bounds__(256) void k_cvt(const float* __restrict__ src,
                                             short* __restrict__ dst) {
  long i = ((long)blockIdx.x * 256 + threadIdx.x) * 8;
  f4v a = *(const f4v*)(src + i);
  f4v b = *(const f4v*)(src + i + 4);
  s8v o;
  o[0] = f2bf(a[0]); o[1] = f2bf(a[1]); o[2] = f2bf(a[2]); o[3] = f2bf(a[3]);
  o[4] = f2bf(b[0]); o[5] = f2bf(b[1]); o[6] = f2bf(b[2]); o[7] = f2bf(b[3]);
  *(s8v*)(dst + i) = o;
}

// ---- fp32-input bf16 MFMA GEMM (MODE 2: scatter to embp2 packed layout) ----
template <int MODE>
__global__ __launch_bounds__(256) void gemm_bf16(
    const float* __restrict__ A, const float* __restrict__ B,
    const int* __restrict__ a_rows, const float* __restrict__ bias,
    float* __restrict__ C, int K, int lda, int ldb, int ldc) {
  __shared__ short As[128 * 72];
  __shared__ short Bs[128 * 72];
  int n0 = blockIdx.x * 128, m0 = blockIdx.y * 128;
  int t = threadIdx.x;
  int lane = t & 63, w = t >> 6;
  int wm = w & 1, wn = w >> 1;
  f4v acc[4][4];
#pragma unroll
  for (int mi = 0; mi < 4; ++mi)
#pragma unroll
    for (int ni = 0; ni < 4; ++ni) acc[mi][ni] = (f4v){0.f, 0.f, 0.f, 0.f};

  int sr = t >> 1;
  int sh = (t & 1) * 32;
  long arow = a_rows ? (long)a_rows[m0 + sr] : (long)(m0 + sr);
  const float* ap = A + arow * lda + sh;
  const float* bp = B + (long)(n0 + sr) * ldb + sh;
  short* as = &As[sr * 72 + sh];
  short* bs = &Bs[sr * 72 + sh];

  for (int k0 = 0; k0 < K; k0 += 64) {
#pragma unroll
    for (int i = 0; i < 8; ++i) {
      f4v va = *(const f4v*)(ap + k0 + i * 4);
      f4v vb = *(const f4v*)(bp + k0 + i * 4);
      s4v sa, sb;
      sa[0] = f2bf(va[0]); sa[1] = f2bf(va[1]); sa[2] = f2bf(va[2]); sa[3] = f2bf(va[3]);
      sb[0] = f2bf(vb[0]); sb[1] = f2bf(vb[1]); sb[2] = f2bf(vb[2]); sb[3] = f2bf(vb[3]);
      *(s4v*)(as + i * 4) = sa;
      *(s4v*)(bs + i * 4) = sb;
    }
    __syncthreads();
#pragma unroll
    for (int ks = 0; ks < 2; ++ks) {
      s8v af[4], bf[4];
#pragma unroll
      for (int mi = 0; mi < 4; ++mi)
        af[mi] = *(const s8v*)&As[(wm * 64 + mi * 16 + (lane & 15)) * 72 + ks * 32 + (lane >> 4) * 8];
#pragma unroll
      for (int ni = 0; ni < 4; ++ni)
        bf[ni] = *(const s8v*)&Bs[(wn * 64 + ni * 16 + (lane & 15)) * 72 + ks * 32 + (lane >> 4) * 8];
#pragma unroll
      for (int mi = 0; mi < 4; ++mi)
#pragma unroll
        for (int ni = 0; ni < 4; ++ni)
          acc[mi][ni] = __builtin_amdgcn_mfma_f32_16x16x32_bf16(af[mi], bf[ni], acc[mi][ni], 0, 0, 0);
    }
    __syncthreads();
  }
  int fq = lane >> 4, fr = lane & 15;
#pragma unroll
  for (int mi = 0; mi < 4; ++mi)
#pragma unroll
    for (int ni = 0; ni < 4; ++ni) {
      int col = n0 + wn * 64 + ni * 16 + fr;
      long rowb = m0 + wm * 64 + mi * 16 + fq * 4;
      if (MODE == 2) {
        int bz = (col & 511) >> 2;
        int c = ((col >> 9) << 2) + (col & 3);
#pragma unroll
        for (int r = 0; r < 4; ++r) {
          long m = rowb + r;  // = b*64 + t
          C[(long)bz * 32768 + (m & 63) * 512 + (m >> 6) * 16 + c] = acc[mi][ni][r];
        }
      } else {
        float bv = bias ? bias[col] : 0.f;
#pragma unroll
        for (int r = 0; r < 4; ++r) C[(rowb + r) * (long)ldc + col] = acc[mi][ni][r] + bv;
      }
    }
}

// ---- output GEMM: A bf16 [2048][512], B bf16 (or fp32 if BCVT) [32000][512] -
// grid: x = m-tiles (16), y = n-tiles (250) so B n-slices stay L2/L3-hot.
template <bool BCVT>
__global__ __launch_bounds__(256) void gemm_out(
    const short* __restrict__ A, const short* __restrict__ Bbf,
    const float* __restrict__ Bf, const float* __restrict__ bias,
    float* __restrict__ C) {
  __shared__ short As[128 * 72];
  __shared__ short Bs[128 * 72];
  int m0 = blockIdx.x * 128, n0 = blockIdx.y * 128;
  int t = threadIdx.x;
  int lane = t & 63, w = t >> 6;
  int wm = w & 1, wn = w >> 1;
  f4v acc[4][4];
#pragma unroll
  for (int mi = 0; mi < 4; ++mi)
#pragma unroll
    for (int ni = 0; ni < 4; ++ni) acc[mi][ni] = (f4v){0.f, 0.f, 0.f, 0.f};

  int sr = t >> 1;
  int sh = (t & 1) * 32;
  const short* ap = A + (long)(m0 + sr) * 512 + sh;
  const short* bpb = Bbf + (long)(n0 + sr) * 512 + sh;
  const float* bpf = Bf + (long)(n0 + sr) * 512 + sh;
  short* as = &As[sr * 72 + sh];
  short* bs = &Bs[sr * 72 + sh];

  for (int k0 = 0; k0 < 512; k0 += 64) {
#pragma unroll
    for (int i = 0; i < 4; ++i)
      *(s8v*)(as + i * 8) = *(const s8v*)(ap + k0 + i * 8);
    if (BCVT) {
#pragma unroll
      for (int i = 0; i < 8; ++i) {
        f4v vb = *(const f4v*)(bpf + k0 + i * 4);
        s4v sb;
        sb[0] = f2bf(vb[0]); sb[1] = f2bf(vb[1]); sb[2] = f2bf(vb[2]); sb[3] = f2bf(vb[3]);
        *(s4v*)(bs + i * 4) = sb;
      }
    } else {
#pragma unroll
      for (int i = 0; i < 4; ++i)
        *(s8v*)(bs + i * 8) = *(const s8v*)(bpb + k0 + i * 8);
    }
    __syncthreads();
#pragma unroll
    for (int ks = 0; ks < 2; ++ks) {
      s8v af[4], bf[4];
#pragma unroll
      for (int mi = 0; mi < 4; ++mi)
        af[mi] = *(const s8v*)&As[(wm * 64 + mi * 16 + (lane & 15)) * 72 + ks * 32 + (lane >> 4) * 8];
#pragma unroll
      for (int ni = 0; ni < 4; ++ni)
        bf[ni] = *(const s8v*)&Bs[(wn * 64 + ni * 16 + (lane & 15)) * 72 + ks * 32 + (lane >> 4) * 8];
#pragma unroll
      for (int mi = 0; mi < 4; ++mi)
#pragma unroll
        for (int ni = 0; ni < 4; ++ni)
          acc[mi][ni] = __builtin_amdgcn_mfma_f32_16x16x32_bf16(af[mi], bf[ni], acc[mi][ni], 0, 0, 0);
    }
    __syncthreads();
  }
  int fq = lane >> 4, fr = lane & 15;
#pragma unroll
  for (int mi = 0; mi < 4; ++mi)
#pragma unroll
    for (int ni = 0; ni < 4; ++ni) {
      int col = n0 + wn * 64 + ni * 16 + fr;
      float bv = bias[col];
      long rowb = m0 + wm * 64 + mi * 16 + fq * 4;
#pragma unroll
      for (int r = 0; r < 4; ++r)
        __builtin_nontemporal_store(acc[mi][ni][r] + bv, &C[(rowb + r) * 32000L + col]);
    }
}

// ---- persistent fused 2-layer LSTM: BLOCK-SPECIALIZED twin pipelines --------
// (r9 structure — proven 317 us.) 256 blocks x 256 threads: [0,128) = layer-0
// pipeline (owns 4 h0-dims), [128,256) = layer-1 pipeline (owns 4 h1-dims).
__global__ __launch_bounds__(256, 1) void lstm_persist(
    const float* __restrict__ w_hh0, const float* __restrict__ w_ih1,
    const float* __restrict__ w_hh1,
    const float* __restrict__ b_ih1, const float* __restrict__ b_hh1,
    const float* __restrict__ enc_c,
    const float* __restrict__ embp2, const float* __restrict__ ctxpre,
    short* __restrict__ hbuf, short* __restrict__ h1seqbf,
    unsigned* __restrict__ arr) {
  __shared__ alignas(16) short wlds[6 * WROWS];  // l0: 2 slices; l1: 4 slices
  __shared__ float ctxp_l[32][16];               // l0 only
  __shared__ float bias1_l[16];                  // l1 only
  __shared__ float gbuf[2][32][17];              // [kh][batch][gatecol]

  const int tid = threadIdx.x;
  const bool is_l0 = (blockIdx.x < NBLK);
  const int bz = is_l0 ? blockIdx.x : blockIdx.x - NBLK;
  const int hb4 = bz * 4;
  const int lane = tid & 63, wid = tid >> 6;
  const int mt = wid & 1, kh = wid >> 1;
  const int fr = lane & 15, fq = lane >> 4;

  const int nmat = is_l0 ? 1 : 2;
  for (int base = tid * 4; base < nmat * 16 * 512; base += 1024) {
    int row = base >> 9, k = base & 511;
    int m = row >> 4, c = row & 15;
    int j = ((c >> 2) << 9) + hb4 + (c & 3);
    const float* wsrc = is_l0 ? w_hh0 : (m == 0 ? w_ih1 : w_hh1);
    f4v v = *(const f4v*)(wsrc + (long)j * 512 + k);
    short* hi = &wlds[(m * 2) * WROWS + c * PADK + k];
    short* lo = &wlds[(m * 2 + 1) * WROWS + c * PADK + k];
#pragma unroll
    for (int e = 0; e < 4; ++e) {
      short hh = f2bf(v[e]);
      hi[e] = hh;
      lo[e] = f2bf(v[e] - bf2f(hh));
    }
  }
  if (is_l0) {
    for (int i = tid; i < 512; i += 256) {
      int b = i >> 4, c = i & 15;
      ctxp_l[b][c] = ctxpre[b * 2048 + ((c >> 2) << 9) + hb4 + (c & 3)];
    }
  } else if (tid < 16) {
    int j = ((tid >> 2) << 9) + hb4 + (tid & 3);
    bias1_l[tid] = b_ih1[j] + b_hh1[j];
  }
  const int cq = (tid & 127) >> 2, cr = tid & 3;
  float cst = 0.f;
  if (tid < 128)
    cst = enc_c[(is_l0 ? 0 : 16384) + cq * 512 + hb4 + cr];
  __syncthreads();
  asm volatile("s_waitcnt vmcnt(0)" ::: "memory");
  asm volatile("buffer_inv sc1" ::: "memory");
  __syncthreads();

  short* H0 = hbuf;                        // + slot*HSLOT
  short* H1 = hbuf + (long)65 * HSLOT;
  const int foff = (mt * 16 + fr) * 512 + kh * 256 + fq * 8;
  const int woff = fr * PADK + kh * 256 + fq * 8;

  if (is_l0) {
    // =================== layer-0 pipeline: p = 0..63 =====================
    for (int p = 0; p < 64; ++p) {
      float e4[4];
      if (tid < 128) {
        const float* ep = embp2 + (long)bz * 32768 + p * 512 + cq * 16 + cr;
#pragma unroll
        for (int g = 0; g < 4; ++g) e4[g] = ep[g * 4];
      }
      if (p) {
        if (tid < NBLK)
          while (__hip_atomic_load(&arr[tid << 5], __ATOMIC_RELAXED,
                                   __HIP_MEMORY_SCOPE_AGENT) < (unsigned)p)
            __builtin_amdgcn_s_sleep(1);
        __syncthreads();
      }
      const short* a0 = H0 + (long)p * HSLOT + foff;
      f4v l0h = {0.f, 0.f, 0.f, 0.f}, l0l = l0h;
      const short* b0h = &wlds[0 * WROWS + woff];
      const short* b0l = &wlds[1 * WROWS + woff];
#pragma unroll
      for (int ks = 0; ks < 8; ++ks) {
        s8v A0 = *(const s8v*)(a0 + ks * 32);
        s8v B0h = *(const s8v*)(b0h + ks * 32);
        s8v B0l = *(const s8v*)(b0l + ks * 32);
        l0h = __builtin_amdgcn_mfma_f32_16x16x32_bf16(A0, B0h, l0h, 0, 0, 0);
        l0l = __builtin_amdgcn_mfma_f32_16x16x32_bf16(A0, B0l, l0l, 0, 0, 0);
      }
      f4v s = l0h + l0l;
#pragma unroll
      for (int r = 0; r < 4; ++r) gbuf[kh][mt * 16 + fq * 4 + r][fr] = s[r];
      __syncthreads();
      if (tid < 128) {
        float g4[4];
#pragma unroll
        for (int g = 0; g < 4; ++g) {
          int c = g * 4 + cr;
          g4[g] = gbuf[0][cq][c] + gbuf[1][cq][c] + ctxp_l[cq][c] + e4[g];
        }
        float cn = sigm(g4[1]) * cst + sigm(g4[0]) * tanhf(g4[2]);
        float hn = sigm(g4[3]) * tanhf(cn);
        cst = cn;
        unsigned v16 = (unsigned)(unsigned short)f2bf(hn);
        unsigned p01 = v16 | ((unsigned)__shfl_down((int)v16, 1) << 16);
        unsigned long long wd = (unsigned long long)p01 |
            ((unsigned long long)(unsigned)__shfl_down((int)p01, 2) << 32);
        if ((tid & 3) == 0)
          cstore64(H0 + (long)(p + 1) * HSLOT + cq * 512 + hb4, wd);
      }
      asm volatile("s_waitcnt vmcnt(0)" ::: "memory");
      __syncthreads();
      if (tid == 0)
        __hip_atomic_store(&arr[(unsigned)bz << 5], (unsigned)(p + 1),
                           __ATOMIC_RELAXED, __HIP_MEMORY_SCOPE_AGENT);
    }
  } else {
    // =================== layer-1 pipeline: p = 1..64 =====================
    for (int p = 1; p <= 64; ++p) {
      if (tid < NBLK)
        while (__hip_atomic_load(&arr[tid << 5], __ATOMIC_RELAXED,
                                 __HIP_MEMORY_SCOPE_AGENT) < (unsigned)p)
          __builtin_amdgcn_s_sleep(2);
      __syncthreads();
      const short* a0 = H0 + (long)p * HSLOT + foff;
      f4v x1h = {0.f, 0.f, 0.f, 0.f}, x1l = x1h, h1h = x1h, h1l = x1h;
      const short* b2h = &wlds[0 * WROWS + woff];
      const short* b2l = &wlds[1 * WROWS + woff];
#pragma unroll
      for (int ks = 0; ks < 8; ++ks) {
        s8v A0 = *(const s8v*)(a0 + ks * 32);
        s8v B2h = *(const s8v*)(b2h + ks * 32);
        s8v B2l = *(const s8v*)(b2l + ks * 32);
        x1h = __builtin_amdgcn_mfma_f32_16x16x32_bf16(A0, B2h, x1h, 0, 0, 0);
        x1l = __builtin_amdgcn_mfma_f32_16x16x32_bf16(A0, B2l, x1l, 0, 0, 0);
      }
      if (p > 1) {
        if (tid < NBLK)
          while (__hip_atomic_load(&arr[(tid << 5) + 16], __ATOMIC_RELAXED,
                                   __HIP_MEMORY_SCOPE_AGENT) < (unsigned)(p - 1))
            __builtin_amdgcn_s_sleep(2);
        __syncthreads();
      }
      const short* a1 = H1 + (long)(p - 1) * HSLOT + foff;
      const short* b4h = &wlds[2 * WROWS + woff];
      const short* b4l = &wlds[3 * WROWS + woff];
#pragma unroll
      for (int ks = 0; ks < 8; ++ks) {
        s8v A1 = *(const s8v*)(a1 + ks * 32);
        s8v B4h = *(const s8v*)(b4h + ks * 32);
        s8v B4l = *(const s8v*)(b4l + ks * 32);
        h1h = __builtin_amdgcn_mfma_f32_16x16x32_bf16(A1, B4h, h1h, 0, 0, 0);
        h1l = __builtin_amdgcn_mfma_f32_16x16x32_bf16(A1, B4l, h1l, 0, 0, 0);
      }
      f4v s = x1h + x1l + h1h + h1l;
#pragma unroll
      for (int r = 0; r < 4; ++r) gbuf[kh][mt * 16 + fq * 4 + r][fr] = s[r];
      __syncthreads();
      if (tid < 128) {
        float g4[4];
#pragma unroll
        for (int g = 0; g < 4; ++g) {
          int c = g * 4 + cr;
          g4[g] = gbuf[0][cq][c] + gbuf[1][cq][c] + bias1_l[c];
        }
        float cn = sigm(g4[1]) * cst + sigm(g4[0]) * tanhf(g4[2]);
        float hn = sigm(g4[3]) * tanhf(cn);
        cst = cn;
        unsigned v16 = (unsigned)(unsigned short)f2bf(hn);
        unsigned p01 = v16 | ((unsigned)__shfl_down((int)v16, 1) << 16);
        unsigned long long wd = (unsigned long long)p01 |
            ((unsigned long long)(unsigned)__shfl_down((int)p01, 2) << 32);
        if ((tid & 3) == 0) {
          if (p < 64)  // slot 64 never read (h1seq carries step 63)
            cstore64(H1 + (long)p * HSLOT + cq * 512 + hb4, wd);
          *(unsigned long long*)&h1seqbf[((long)cq * 64 + (p - 1)) * 512 + hb4] = wd;
        }
      }
      if (p < 64) {
        asm volatile("s_waitcnt vmcnt(0)" ::: "memory");
        __syncthreads();
        if (tid == 0)
          __hip_atomic_store(&arr[((unsigned)bz << 5) + 16], (unsigned)p,
                             __ATOMIC_RELAXED, __HIP_MEMORY_SCOPE_AGENT);
      }
    }
  }
}

extern "C" void kernel_launch(void* const* d_in, const int* in_sizes, int n_in,
                              void* d_out, int out_size, void* d_ws, size_t ws_size,
                              hipStream_t stream) {
  const int*   tokens  = (const int*)  d_in[0];
  const float* enc_out = (const float*)d_in[1];
  const float* enc_h   = (const float*)d_in[2];
  const float* enc_c   = (const float*)d_in[3];
  const float* emb     = (const float*)d_in[4];
  const float* attn1_w = (const float*)d_in[5];
  const float* attn2_w = (const float*)d_in[7];
  const float* w_ih0   = (const float*)d_in[9];
  const float* w_hh0   = (const float*)d_in[10];
  const float* b_ih0   = (const float*)d_in[11];
  const float* b_hh0   = (const float*)d_in[12];
  const float* w_ih1   = (const float*)d_in[13];
  const float* w_hh1   = (const float*)d_in[14];
  const float* b_ih1   = (const float*)d_in[15];
  const float* b_hh1   = (const float*)d_in[16];
  const float* out_w   = (const float*)d_in[17];
  const float* out_b   = (const float*)d_in[18];
  float* out = (float*)d_out;

  float* f = (float*)d_ws;
  float*    w_enc    = f;                        // [0, 1024)
  float*    ctx      = f + 1024;                 // [1024, 33792)
  float*    ctxpre   = f + 33792;                // [33792, 99328)
  float*    embp2    = f + 99328;                // [99328, 4293632)
  short*    h1seqbf  = (short*)(f + 4293632);    // 1,048,576 shorts -> 4817920
  short*    hbuf     = (short*)(f + 4817920);    // 130 x 16384 shorts -> 5882880
  unsigned* arr      = (unsigned*)(f + 5882880); // 4128 uints -> 5887008
  float*    logits   = f + 5887040;              // 4096 floats -> 5891136
  short*    out_w_bf = (short*)(f + 5891200);    // 16,384,000 shorts (optional)
  const size_t NEED = (size_t)(5891200 + 8192000) * 4;
  const bool big = ws_size >= NEED;

  k_init2<<<64, 256, 0, stream>>>(enc_h, hbuf, arr);
  k_weff<<<32, 256, 0, stream>>>(attn1_w, attn2_w, w_enc);
  k_attn_lg<<<256, 256, 0, stream>>>(enc_out, w_enc, logits);
  k_attn_cx<<<128, 256, 0, stream>>>(enc_out, logits, ctx);
  k_ctxpre<<<256, 256, 0, stream>>>(w_ih0, b_ih0, b_hh0, ctx, ctxpre);
  gemm_bf16<2><<<dim3(16, 16), 256, 0, stream>>>(emb, w_ih0, tokens, nullptr,
                                                 embp2, 512, 512, 1536, 0);
  if (big) k_cvt<<<8000, 256, 0, stream>>>(out_w, out_w_bf);
  lstm_persist<<<2 * NBLK, 256, 0, stream>>>(w_hh0, w_ih1, w_hh1, b_ih1, b_hh1,
                                             enc_c, embp2, ctxpre, hbuf,
                                             h1seqbf, arr);
  if (big)
    gemm_out<false><<<dim3(16, 250), 256, 0, stream>>>(h1seqbf, out_w_bf, nullptr,
                                                       out_b, out);
  else
    gemm_out<true><<<dim3(16, 250), 256, 0, stream>>>(h1seqbf, nullptr, out_w,
                                                      out_b, out);
}